// Round 1
// baseline (573.804 us; speedup 1.0000x reference)
//
#include <hip/hip_runtime.h>
#include <hip/hip_bf16.h>
#include <math.h>

// Problem constants
#define BB 2
#define CC 64
#define HH 256
#define WW 256
#define OO 64
#define KK 3
#define K2 9
#define HW (HH*WW)          // 65536
#define CHW (CC*HW)

// ws layout (floats):
//  wt   [576*27]   : combined offset+amp conv weights, transposed [s][27]
//  wt3  [576*64]   : w3d transposed [s][o]
//  ys   [B*9*HW]
//  xs   [B*9*HW]
//  av   [B*9*HW]
#define WT_OFF   0
#define WT3_OFF  (576*27)                 // 15552
#define YS_OFF   (WT3_OFF + 576*64)       // 52416
#define XS_OFF   (YS_OFF + BB*K2*HW)      // +1179648
#define AV_OFF   (XS_OFF + BB*K2*HW)
#define WS_FLOATS (AV_OFF + BB*K2*HW)

__global__ __launch_bounds__(256) void k_prep(
    const float* __restrict__ offw, const float* __restrict__ ampw,
    const float* __restrict__ w3d, float* __restrict__ wt, float* __restrict__ wt3)
{
    int i = blockIdx.x * 256 + threadIdx.x;
    const int total = 576*27 + 576*64;
    for (; i < total; i += gridDim.x * 256) {
        if (i < 576*27) {
            int s = i / 27, ch = i % 27;
            wt[i] = (ch < 18) ? offw[ch*576 + s] : ampw[(ch-18)*576 + s];
        } else {
            int j = i - 576*27;
            int s = j >> 6, o = j & 63;
            wt3[j] = w3d[o*576 + s];
        }
    }
}

// Kernel 1: offset conv (18 ch) + amp conv (9 ch), thread per output pixel.
// Writes clipped padded-space sample coords and sigmoid amplitude.
__global__ __launch_bounds__(256) void k_offsets(
    const float* __restrict__ x, const float* __restrict__ wt,
    const float* __restrict__ offb, const float* __restrict__ ampb,
    float* __restrict__ ys, float* __restrict__ xs, float* __restrict__ av)
{
    const int w = threadIdx.x;
    const int bh = blockIdx.x;
    const int h = bh & 255;
    const int b = bh >> 8;

    float acc[27];
#pragma unroll
    for (int i = 0; i < 27; ++i) acc[i] = 0.f;

    const float* xb = x + (size_t)b * CHW;
    for (int c = 0; c < CC; ++c) {
        const float* xc = xb + c * HW;
#pragma unroll
        for (int ky = 0; ky < 3; ++ky) {
            const int iy = h + ky - 1;
            const bool rowok = (unsigned)iy < 256u;
            const float* xr = xc + iy * WW;
#pragma unroll
            for (int kx = 0; kx < 3; ++kx) {
                const int ix = w + kx - 1;
                const float v = (rowok && (unsigned)ix < 256u) ? xr[ix] : 0.f;
                const int s = c*9 + ky*3 + kx;
                const float* wr = wt + s*27;   // uniform address -> scalar loads
#pragma unroll
                for (int ch = 0; ch < 27; ++ch)
                    acc[ch] = fmaf(v, wr[ch], acc[ch]);
            }
        }
    }

    const int pix = h * WW + w;
    const size_t base = (size_t)b * K2 * HW;
#pragma unroll
    for (int k = 0; k < K2; ++k) {
        const float yoff = acc[2*k]     + offb[2*k];
        const float xoff = acc[2*k + 1] + offb[2*k + 1];
        const int ky = k / 3, kx = k % 3;
        float yy = (float)(h + ky) + yoff;
        float xx = (float)(w + kx) + xoff;
        yy = fminf(fmaxf(yy, 0.f), 257.f);
        xx = fminf(fmaxf(xx, 0.f), 257.f);
        float aa = acc[18 + k] + ampb[k];
        aa = 1.f / (1.f + expf(-aa));
        ys[base + k*HW + pix] = yy;
        xs[base + k*HW + pix] = xx;
        av[base + k*HW + pix] = aa;
    }
}

// Kernel 2: bilinear sampling + modulation + [576 x 32] contraction + ReLU.
// Each block: one (b, h, o-half); thread = w. 36.9 KB LDS of weights.
__global__ __launch_bounds__(256) void k_main(
    const float* __restrict__ x, const float* __restrict__ wt3,
    const float* __restrict__ ys, const float* __restrict__ xs,
    const float* __restrict__ av, float* __restrict__ out)
{
    __shared__ float wl[576 * 32];
    const int tid = threadIdx.x;
    int blk = blockIdx.x;
    const int ohalf = blk & 1; blk >>= 1;
    const int h = blk & 255;
    const int b = blk >> 8;

    // stage weights: wl[s*32 + j] = w3d[(32*ohalf + j)][s]
    for (int i = tid; i < 576*32; i += 256) {
        int s = i >> 5, j = i & 31;
        wl[i] = wt3[(s << 6) + ohalf*32 + j];
    }
    __syncthreads();

    float acc[32];
#pragma unroll
    for (int i = 0; i < 32; ++i) acc[i] = 0.f;

    const int w = tid;
    const float* xb = x + (size_t)b * CHW;
    size_t sb = (size_t)b * K2 * HW + h * WW + w;

    for (int k = 0; k < K2; ++k) {
        const float yy = ys[sb];
        const float xx = xs[sb];
        const float aa = av[sb];
        sb += HW;

        const float y0f = floorf(yy), x0f = floorf(xx);
        const float y1f = fminf(y0f + 1.f, 257.f);
        const float x1f = fminf(x0f + 1.f, 257.f);
        const float ay = yy - y0f, by = y1f - yy;
        const float ax = xx - x0f, bx = x1f - xx;

        const int r0 = (int)y0f - 1, r1 = (int)y1f - 1;
        const int c0 = (int)x0f - 1, c1 = (int)x1f - 1;
        const bool vy0 = (unsigned)r0 < 256u, vy1 = (unsigned)r1 < 256u;
        const bool vx0 = (unsigned)c0 < 256u, vx1 = (unsigned)c1 < 256u;

        float w00 = by*bx*aa, w01 = by*ax*aa, w10 = ay*bx*aa, w11 = ay*ax*aa;
        int o00, o01, o10, o11;
        if (vy0 && vx0) o00 = r0*WW + c0; else { o00 = 0; w00 = 0.f; }
        if (vy0 && vx1) o01 = r0*WW + c1; else { o01 = 0; w01 = 0.f; }
        if (vy1 && vx0) o10 = r1*WW + c0; else { o10 = 0; w10 = 0.f; }
        if (vy1 && vx1) o11 = r1*WW + c1; else { o11 = 0; w11 = 0.f; }

        const float* pc = xb;
#pragma unroll 2
        for (int c = 0; c < CC; ++c) {
            const float v = w00*pc[o00] + w01*pc[o01] + w10*pc[o10] + w11*pc[o11];
            pc += HW;
            const float4* wr = (const float4*)&wl[((c*9 + k) << 5)];
#pragma unroll
            for (int j = 0; j < 8; ++j) {
                const float4 wv = wr[j];
                acc[4*j + 0] = fmaf(v, wv.x, acc[4*j + 0]);
                acc[4*j + 1] = fmaf(v, wv.y, acc[4*j + 1]);
                acc[4*j + 2] = fmaf(v, wv.z, acc[4*j + 2]);
                acc[4*j + 3] = fmaf(v, wv.w, acc[4*j + 3]);
            }
        }
    }

    const size_t ob = ((size_t)b * OO + ohalf*32) * HW + h * WW + w;
#pragma unroll
    for (int j = 0; j < 32; ++j)
        out[ob + (size_t)j * HW] = fmaxf(acc[j], 0.f);
}

extern "C" void kernel_launch(void* const* d_in, const int* in_sizes, int n_in,
                              void* d_out, int out_size, void* d_ws, size_t ws_size,
                              hipStream_t stream) {
    const float* x    = (const float*)d_in[0];
    const float* offw = (const float*)d_in[1];
    const float* offb = (const float*)d_in[2];
    const float* ampw = (const float*)d_in[3];
    const float* ampb = (const float*)d_in[4];
    const float* w3d  = (const float*)d_in[5];
    float* out = (float*)d_out;
    float* ws  = (float*)d_ws;

    float* wt  = ws + WT_OFF;
    float* wt3 = ws + WT3_OFF;
    float* ys  = ws + YS_OFF;
    float* xs  = ws + XS_OFF;
    float* av  = ws + AV_OFF;

    k_prep<<<64, 256, 0, stream>>>(offw, ampw, w3d, wt, wt3);
    k_offsets<<<BB*HH, 256, 0, stream>>>(x, wt, offb, ampb, ys, xs, av);
    k_main<<<BB*HH*2, 256, 0, stream>>>(x, wt3, ys, xs, av, out);
}